// Round 2
// baseline (246.413 us; speedup 1.0000x reference)
//
#include <hip/hip_runtime.h>

// FourierFeatureMLP fused kernel for MI355X (gfx950). Round 7.
//
// vs round 6 (202 us; MfmaUtil 29%, VALUBusy 41%): dominant consumer was
// L2 weight refetch: every wave reads all 1 MiB weights per layer-pass ->
// 4 GB L2 traffic = ~60% of wall (293k cyc/CU vs MFMA 159k). Fix: split
// the A-operand across pipes. Half the weights (mt 0-1) staged into LDS
// once per BLOCK via global_load_lds (dbuf by chunk parity, 1 syncthreads
// per chunk; stage for c+1 issued at top of c -> full chunk to land, m97
// pattern). Other half (mt 2-3) direct from global; the block's 4
// chunk-synced waves share the 16 KB window through L1. Weight bytes now
// spread over LDS + L1/L2, each pipe ~at/below the MFMA floor.
// Biases pre-scaled (*2/ln2) into a table by the convert kernel.
//
// Layouts (MFMA 16x16x32, learn_hip-verified):
//   A: lane holds A[m=lane&15][k=quad*8+j]   (W fragment)
//   B: lane holds B[k=quad*8+j][n=lane&15]   (h fragment, n = point)
//   D: n(point)=lane&15, m(unit)=quad*4+reg
// Weights fragment-major: frag = ((layer*4+c)*4+mt)*8+kt, 1 KB each,
// addr = frag*1024 + lane*16 -> coalesced b128 / gload_lds-compatible.

#define HDIM   256
#define NLAYER 8
#define PTSW   32
#define NTHR   256
#define TILE_N 128
#define WHALVES (NLAYER * HDIM * HDIM)

typedef __attribute__((ext_vector_type(8))) _Float16 half8;
typedef __attribute__((ext_vector_type(4))) _Float16 half4;
typedef __attribute__((ext_vector_type(2))) _Float16 half2;
typedef __attribute__((ext_vector_type(4))) float float4v;

__device__ __forceinline__ half2 pk2(float a, float b) {
    return __builtin_bit_cast(half2, __builtin_amdgcn_cvt_pkrtz(a, b));
}

// tanh(acc + b) with pre-scaled bias bK = b * 2/ln2:
// t = acc*K + bK; z = 2^t; r = 1/(1+z); tanh = 1 - 2r. Saturation-safe.
#define TANH_K 2.885390081777927f
__device__ __forceinline__ float fast_tanh_fused(float acc, float bK) {
    float z = __builtin_amdgcn_exp2f(fmaf(acc, TANH_K, bK));
    float r = __builtin_amdgcn_rcpf(z + 1.0f);
    return fmaf(-2.0f, r, 1.0f);
}

// ---- pre-pass: fp32 -> fp16 weights, permuted to FRAGMENT-major order,
// plus pre-scaled f32 bias table bK[layer*256+u] at halfs offset WHALVES.
__global__ void convert_w_kernel(const float* __restrict__ W_in,
                                 const float* __restrict__ W_h,
                                 const float* __restrict__ b_in,
                                 const float* __restrict__ b_h,
                                 _Float16* __restrict__ dst)
{
    const int i = blockIdx.x * blockDim.x + threadIdx.x;   // 0 .. WHALVES-1
    const int j     = i & 7;
    const int lane  = (i >> 3) & 63;
    const int frag  = i >> 9;
    const int kt    = frag & 7;
    const int mt    = (frag >> 3) & 3;
    const int c     = (frag >> 5) & 3;
    const int layer = frag >> 7;
    const int u = c * 64 + mt * 16 + (lane & 15);
    const int k = kt * 32 + (lane >> 4) * 8 + j;
    const float v = (layer == 0) ? W_in[u * HDIM + k]
                                 : W_h[((layer - 1) * HDIM + u) * HDIM + k];
    dst[i] = (_Float16)v;

    if (i < NLAYER * HDIM) {                               // bias table
        float* bk = (float*)(dst + WHALVES);
        const int l = i >> 8, uu = i & 255;
        const float b = (l == 0) ? b_in[uu] : b_h[(l - 1) * HDIM + uu];
        bk[i] = b * TANH_K;
    }
}

// stage one 16 KB half-chunk into LDS: 4 wave-issues of 1 KB each.
// gsrc points at the half-chunk base (halfs); ldst is the LDS base.
__device__ __forceinline__ void stage_half(const _Float16* __restrict__ gsrc,
                                           _Float16* __restrict__ ldst,
                                           const int wave, const int lane)
{
    #pragma unroll
    for (int i = 0; i < 4; ++i) {
        const int off = (wave * 4 + i) * 512;              // halfs, wave-uniform
        __builtin_amdgcn_global_load_lds(
            (const __attribute__((address_space(1))) void*)(gsrc + off + lane * 8),
            (__attribute__((address_space(3))) void*)(ldst + off),
            16, 0, 0);
    }
}

// One dense layer for one wave: hin (B-frags, regs) -> hout (B-frags, regs).
__device__ __forceinline__ void layer_step(const int l,
                                           const _Float16* __restrict__ Wall,
                                           const float* __restrict__ bK,
                                           _Float16 (&wbuf)[2][8192],
                                           _Float16* __restrict__ lbuf,
                                           const int wave, const int lane,
                                           const int laneM, const int quad,
                                           const half8 (&hin)[2][8],
                                           half8 (&hout)[2][8])
{
    #pragma unroll
    for (int c = 0; c < 4; ++c) {
        __syncthreads();   // stage(l,c) visible to all; buf[(c+1)&1] free

        // issue stage for the NEXT chunk-step (skip after the very last)
        const int step = l * 4 + c;
        if (step < NLAYER * 4 - 1)
            stage_half(Wall + ((step + 1) & 31) * 16384,
                       &wbuf[(c + 1) & 1][0], wave, lane);

        const _Float16* __restrict__ wl = &wbuf[c & 1][0];                 // mt 0-1
        const _Float16* __restrict__ wg = Wall + step * 16384 + 8192;      // mt 2-3

        float4v acc[4][2];
        #pragma unroll
        for (int mt = 0; mt < 4; ++mt)
            #pragma unroll
            for (int nt = 0; nt < 2; ++nt)
                acc[mt][nt] = (float4v){0.f, 0.f, 0.f, 0.f};

        half8 a[4], an[4];
        a[0] = *(const half8*)&wl[(0 * 8 + 0) * 512 + lane * 8];
        a[1] = *(const half8*)&wl[(1 * 8 + 0) * 512 + lane * 8];
        a[2] = *(const half8*)&wg[(0 * 8 + 0) * 512 + lane * 8];
        a[3] = *(const half8*)&wg[(1 * 8 + 0) * 512 + lane * 8];

        #pragma unroll
        for (int kt = 0; kt < 8; ++kt) {
            if (kt < 7) {
                an[0] = *(const half8*)&wl[(0 * 8 + kt + 1) * 512 + lane * 8];
                an[1] = *(const half8*)&wl[(1 * 8 + kt + 1) * 512 + lane * 8];
                an[2] = *(const half8*)&wg[(0 * 8 + kt + 1) * 512 + lane * 8];
                an[3] = *(const half8*)&wg[(1 * 8 + kt + 1) * 512 + lane * 8];
            }
            #pragma unroll
            for (int mt = 0; mt < 4; ++mt)
                #pragma unroll
                for (int nt = 0; nt < 2; ++nt)
                    acc[mt][nt] = __builtin_amdgcn_mfma_f32_16x16x32_f16(
                        a[mt], hin[nt][kt], acc[mt][nt], 0, 0, 0);
            if (kt < 7) {
                #pragma unroll
                for (int mt = 0; mt < 4; ++mt) a[mt] = an[mt];  // SSA rename
            }
        }

        // epilogue: bias+tanh, pack, wave-private repack through LDS
        float4 bias[4];
        #pragma unroll
        for (int mt = 0; mt < 4; ++mt)
            bias[mt] = *(const float4*)&bK[l * 256 + c * 64 + mt * 16 + quad * 4];

        #pragma unroll
        for (int mt = 0; mt < 4; ++mt) {
            const int c8 = mt * 2 + (quad >> 1);
            #pragma unroll
            for (int nt = 0; nt < 2; ++nt) {
                const int row = nt * 16 + laneM;
                const float v0 = fast_tanh_fused(acc[mt][nt].x, bias[mt].x);
                const float v1 = fast_tanh_fused(acc[mt][nt].y, bias[mt].y);
                const float v2 = fast_tanh_fused(acc[mt][nt].z, bias[mt].z);
                const float v3 = fast_tanh_fused(acc[mt][nt].w, bias[mt].w);
                const half2 lo = pk2(v0, v1);
                const half2 hi = pk2(v2, v3);
                half4 pkv;
                pkv.x = lo.x; pkv.y = lo.y; pkv.z = hi.x; pkv.w = hi.y;
                *(half4*)&lbuf[row * 64 + ((c8 ^ (row & 7)) << 3) + (quad & 1) * 4] = pkv;
            }
        }
        // read back as B-frags for next layer (same wave: DS is in-order)
        #pragma unroll
        for (int kp = 0; kp < 2; ++kp)
            #pragma unroll
            for (int nt = 0; nt < 2; ++nt) {
                const int row = nt * 16 + laneM;
                const int c8r = (kp * 4 + quad) ^ (row & 7);
                hout[nt][c * 2 + kp] = *(const half8*)&lbuf[row * 64 + (c8r << 3)];
            }
    }
}

__device__ __forceinline__ float dot8(const half8 h, const float4 wa, const float4 wb) {
    return (float)h[0]*wa.x + (float)h[1]*wa.y + (float)h[2]*wa.z + (float)h[3]*wa.w
         + (float)h[4]*wb.x + (float)h[5]*wb.y + (float)h[6]*wb.z + (float)h[7]*wb.w;
}

__global__ __launch_bounds__(NTHR, 2)
void ffmlp_kernel(const float* __restrict__ tx,
                  const float* __restrict__ Bf,
                  const _Float16* __restrict__ Wall,
                  const float* __restrict__ W_out,
                  const float* __restrict__ b_out,
                  float* __restrict__ out)
{
    __shared__ __align__(16) _Float16 wbuf[2][8192];   // 32 KB weight dbuf
    __shared__ __align__(16) _Float16 lbuf[4][2048];   // 16 KB repack (per wave 4 KB)

    const int tid   = threadIdx.x;
    const int wave  = tid >> 6;
    const int lane  = tid & 63;
    const int laneM = lane & 15;
    const int quad  = lane >> 4;
    const int p0    = blockIdx.x * TILE_N + wave * PTSW;

    const float* bK = (const float*)(Wall + WHALVES);

    // prologue: stage chunk-step 0 (overlaps the Fourier stage)
    stage_half(Wall, &wbuf[0][0], wave, lane);

    half8 h0[2][8], h1[2][8];

    // -------- stage 1: Fourier features directly into B-frag registers ----
    // k = kq*32 + quad*8 + j ; kq 0..3 -> sin(f=k), kq+4 -> cos(f=k).
    // sin(2*pi*r) = v_sin(fract(r)) : argument in revolutions.
    {
        const float2* txv = (const float2*)tx;
        const float2* Bv  = (const float2*)Bf;
        #pragma unroll
        for (int nt = 0; nt < 2; ++nt) {
            const float2 t = txv[p0 + nt * 16 + laneM];
            #pragma unroll
            for (int kq = 0; kq < 4; ++kq) {
                const int f0 = kq * 32 + quad * 8;
                half8 s8, c8v;
                #pragma unroll
                for (int jj = 0; jj < 8; jj += 2) {
                    const float2 bA = Bv[f0 + jj];
                    const float2 bB = Bv[f0 + jj + 1];
                    const float r0 = __builtin_amdgcn_fractf(t.x * bA.x + t.y * bA.y);
                    const float r1 = __builtin_amdgcn_fractf(t.x * bB.x + t.y * bB.y);
                    const half2 sp = pk2(__builtin_amdgcn_sinf(r0), __builtin_amdgcn_sinf(r1));
                    const half2 cp = pk2(__builtin_amdgcn_cosf(r0), __builtin_amdgcn_cosf(r1));
                    s8[jj] = sp.x;  s8[jj + 1] = sp.y;
                    c8v[jj] = cp.x; c8v[jj + 1] = cp.y;
                }
                h0[nt][kq]     = s8;
                h0[nt][kq + 4] = c8v;
            }
        }
    }

    // -------- stage 2: 8 dense layers --------------------------------------
    _Float16* __restrict__ lw = &lbuf[wave][0];
    #pragma unroll 1
    for (int lp = 0; lp < 4; ++lp) {
        layer_step(2 * lp,     Wall, bK, wbuf, lw, wave, lane, laneM, quad, h0, h1);
        layer_step(2 * lp + 1, Wall, bK, wbuf, lw, wave, lane, laneM, quad, h1, h0);
    }

    // -------- stage 3: output matvec from registers ------------------------
    {
        float s0 = 0.f, s1 = 0.f;
        #pragma unroll
        for (int kt = 0; kt < 8; ++kt) {
            const float4 wa = *(const float4*)&W_out[kt * 32 + quad * 8];
            const float4 wb = *(const float4*)&W_out[kt * 32 + quad * 8 + 4];
            s0 += dot8(h0[0][kt], wa, wb);
            s1 += dot8(h0[1][kt], wa, wb);
        }
        s0 += __shfl_xor(s0, 16); s0 += __shfl_xor(s0, 32);
        s1 += __shfl_xor(s1, 16); s1 += __shfl_xor(s1, 32);
        if (quad == 0) {
            const float bo = b_out[0];
            out[p0 + laneM]      = s0 + bo;
            out[p0 + 16 + laneM] = s1 + bo;
        }
    }
}

extern "C" void kernel_launch(void* const* d_in, const int* in_sizes, int n_in,
                              void* d_out, int out_size, void* d_ws, size_t ws_size,
                              hipStream_t stream) {
    const float* tx    = (const float*)d_in[0];
    const float* Bf    = (const float*)d_in[1];
    const float* W_in  = (const float*)d_in[2];
    const float* b_in  = (const float*)d_in[3];
    const float* W_h   = (const float*)d_in[4];
    const float* b_h   = (const float*)d_in[5];
    const float* W_out = (const float*)d_in[6];
    const float* b_out = (const float*)d_in[7];
    float* out = (float*)d_out;

    _Float16* Wall = (_Float16*)d_ws;   // 1 MiB weights + 8 KB bias table

    const int npts   = in_sizes[0] / 2;
    const int blocks = npts / TILE_N;   // 1024

    convert_w_kernel<<<WHALVES / NTHR, NTHR, 0, stream>>>(W_in, W_h, b_in, b_h, Wall);
    ffmlp_kernel<<<blocks, NTHR, 0, stream>>>(tx, Bf, Wall, W_out, b_out, out);
}